// Round 2
// baseline (570.822 us; speedup 1.0000x reference)
//
#include <hip/hip_runtime.h>

#define LOGZERO -4290774016.0f   // -(65504^2), exactly representable in fp32

constexpr int Bb = 32, Tt = 512, Dd = 512, Vv = 4096;
constexpr int BT = Bb * Tt;

typedef __attribute__((ext_vector_type(8))) short short8;
typedef __attribute__((ext_vector_type(4))) float f32x4;

#define GLOBAL_AS __attribute__((address_space(1)))
#define LDS_AS    __attribute__((address_space(3)))

__device__ __forceinline__ unsigned short f2bf(float f) {
  unsigned int u = __float_as_uint(f);
  u += 0x7FFFu + ((u >> 16) & 1u);   // RNE
  return (unsigned short)(u >> 16);
}

__device__ __forceinline__ float lgadd(float a, float b) {
  float mx = fmaxf(a, b);
  float d  = fabsf(a - b);
  return mx + __logf(1.0f + __expf(-d));
}

// ---- x and W fp32 -> bf16 (one pass) ----
__global__ __launch_bounds__(256) void kConv(const float* __restrict__ x,
                                             const float* __restrict__ W,
                                             unsigned short* __restrict__ Xb,
                                             unsigned short* __restrict__ Wb) {
  size_t i = (size_t)(blockIdx.x * 256 + threadIdx.x) * 4;
  const float* src;
  unsigned short* dst;
  if (i < (size_t)BT * Dd) { src = x + i; dst = Xb + i; }
  else { size_t j = i - (size_t)BT * Dd; src = W + j; dst = Wb + j; }
  float4 v = *(const float4*)src;
  ushort4 h;
  h.x = f2bf(v.x); h.y = f2bf(v.y); h.z = f2bf(v.z); h.w = f2bf(v.w);
  *(ushort4*)dst = h;
}

// ---- m97-style 128x128 bf16 GEMM + fused exp-sum + beam-logit scatter ----
// grid: (BT/128) * (Vv/128) = 128*32 = 4096 blocks, 256 threads (4 waves as 2x2).
__global__ __launch_bounds__(256) void kA(const unsigned short* __restrict__ Xb,
                                          const unsigned short* __restrict__ Wb,
                                          const float* __restrict__ bias,
                                          const int* __restrict__ beam,
                                          const int* __restrict__ blankp,
                                          float* __restrict__ Ssum,
                                          float* __restrict__ selL,
                                          int CB) {
  __shared__ unsigned short Ald[128 * 64];   // 16 KB, xor-swizzled 16B groups
  __shared__ unsigned short Bld[128 * 64];   // 16 KB
  __shared__ int   selv[31];
  __shared__ float selb[31];

  const int tid = threadIdx.x;
  const int tileN = blockIdx.x & 31;
  const int tileM = blockIdx.x >> 5;
  const int row0 = tileM * 128, col0 = tileN * 128;
  const int b = row0 >> 9;                   // 128 | 512: one batch per block

  if (tid < 31) {
    int v = (tid == 0) ? *blankp : beam[b * CB + tid - 1];
    selv[tid] = v;
    selb[tid] = bias[v];
  }

  const int lane = tid & 63, w = tid >> 6;
  const int ln15 = lane & 15, quad = lane >> 4;
  const int wr = w >> 1, wc = w & 1;

  // staging precompute: wave w handles chunks w*8 .. w*8+7 (A: 0..15, B: 16..31)
  const int srow = lane >> 3;                // 0..7 within chunk
  const int g = lane & 7;                    // 16B group within row

  f32x4 acc[4][4];
  #pragma unroll
  for (int ct = 0; ct < 4; ++ct)
    #pragma unroll
    for (int rt = 0; rt < 4; ++rt) acc[ct][rt] = {0.f, 0.f, 0.f, 0.f};

  for (int k0 = 0; k0 < Dd; k0 += 64) {
    __syncthreads();   // prior-iter fragment reads done before overwrite
    #pragma unroll
    for (int j = 0; j < 8; ++j) {
      int c = w * 8 + j;
      bool isA = c < 16;
      int cc = isA ? c : c - 16;
      int r = cc * 8 + srow;                 // 0..127
      int kk = k0 + ((g ^ (r & 7)) << 3);    // swizzled global k-offset
      const unsigned short* gp = isA ? (Xb + (size_t)(row0 + r) * Dd + kk)
                                     : (Wb + (size_t)(col0 + r) * Dd + kk);
      unsigned short* lp = (isA ? Ald : Bld) + cc * 512;   // 1 KB chunk base
      __builtin_amdgcn_global_load_lds((const GLOBAL_AS void*)gp,
                                       (LDS_AS void*)lp, 16, 0, 0);
    }
    __syncthreads();   // drain DMA (compiler emits vmcnt(0) before barrier)

    #pragma unroll
    for (int ks = 0; ks < 64; ks += 32) {
      short8 af[4], bf[4];
      #pragma unroll
      for (int rt = 0; rt < 4; ++rt) {
        int r = wr * 64 + rt * 16 + ln15;
        int grp = (ks >> 3) + quad;
        af[rt] = *(const short8*)&Ald[r * 64 + ((grp ^ (r & 7)) << 3)];
      }
      #pragma unroll
      for (int ct = 0; ct < 4; ++ct) {
        int cl = wc * 64 + ct * 16 + ln15;
        int grp = (ks >> 3) + quad;
        bf[ct] = *(const short8*)&Bld[cl * 64 + ((grp ^ (cl & 7)) << 3)];
      }
      #pragma unroll
      for (int ct = 0; ct < 4; ++ct)
        #pragma unroll
        for (int rt = 0; rt < 4; ++rt)
          acc[ct][rt] = __builtin_amdgcn_mfma_f32_16x16x32_bf16(af[rt], bf[ct], acc[ct][rt], 0, 0, 0);
    }
  }

  // ---- epilogue: row-wise sum(exp(logit+bias)) -> atomics; beam columns -> selL ----
  float bv[4];
  #pragma unroll
  for (int ct = 0; ct < 4; ++ct) bv[ct] = bias[col0 + wc * 64 + ct * 16 + ln15];

  #pragma unroll
  for (int rt = 0; rt < 4; ++rt) {
    #pragma unroll
    for (int r = 0; r < 4; ++r) {
      float s = 0.f;
      #pragma unroll
      for (int ct = 0; ct < 4; ++ct) s += __expf(acc[ct][rt][r] + bv[ct]);
      s += __shfl_xor(s, 1, 64);
      s += __shfl_xor(s, 2, 64);
      s += __shfl_xor(s, 4, 64);
      s += __shfl_xor(s, 8, 64);
      if (ln15 == 0)
        atomicAdd(&Ssum[row0 + wr * 64 + rt * 16 + quad * 4 + r], s);
    }
  }

  const int tbase = (row0 & 511) + wr * 64;
  for (int s = 0; s < 31; ++s) {
    int v = selv[s];
    int local = v - col0 - wc * 64;
    if (local >= 0 && local < 64 && ln15 == (local & 15)) {
      int ct = local >> 4;
      float bvs = selb[s];
      #pragma unroll
      for (int rt = 0; rt < 4; ++rt)
        #pragma unroll
        for (int r = 0; r < 4; ++r) {
          int t = tbase + rt * 16 + quad * 4 + r;
          selL[((size_t)b * Tt + t) * 31 + s] = acc[ct][rt][r] + bvs;
        }
    }
  }
}

// ---- CTC DP + output assembly. grid: B blocks x 256 threads ----
__global__ __launch_bounds__(256) void kC(const float* __restrict__ selL,
                                          const float* __restrict__ Ssum,
                                          const int* __restrict__ xl,
                                          const int* __restrict__ beam,
                                          const int* __restrict__ blankp,
                                          const int* __restrict__ eosp,
                                          float* __restrict__ out,
                                          int Ly, int CB) {
  __shared__ float sl[Tt * 31];     // 63.5 KB raw selected logits
  __shared__ float lgS[Tt];
  __shared__ float lastP1[Tt];
  __shared__ float blankLp[Tt];
  const int b = blockIdx.x, tid = threadIdx.x;

  for (int i = tid; i < Tt * 31; i += 256) sl[i] = selL[(size_t)b * Tt * 31 + i];
  for (int t = tid; t < Tt; t += 256) lgS[t] = __logf(Ssum[b * Tt + t]);
  __syncthreads();

  float* orow = out + (size_t)b * Vv;
  for (int i = tid; i < Vv; i += 256) orow[i] = LOGZERO;

  const int xlb = xl[b];
  float curP = LOGZERO;
  if (tid < 64) {
    const int lane = tid;
    // blank log-probs + prefix sum over t
    float vloc[8];
    float run = 0.f;
    #pragma unroll
    for (int u = 0; u < 8; ++u) {
      int t = lane * 8 + u;
      float bl = sl[t * 31] - lgS[t];
      blankLp[t] = bl;
      run += bl;
      vloc[u] = run;
    }
    float inc = run;
    #pragma unroll
    for (int off = 1; off < 64; off <<= 1) {
      float o = __shfl_up(inc, off, 64);
      if (lane >= off) inc += o;
    }
    float excl = inc - run;
    #pragma unroll
    for (int u = 0; u < 8; ++u) lastP1[lane * 8 + u] = vloc[u] + excl;

    const int kk = (lane < CB) ? lane : (CB - 1);
    float Pn = LOGZERO, Pb = LOGZERO;
    float mrun = -3.0e38f, srun = 0.0f;
    int start = (Ly < Tt - 1) ? Ly : (Tt - 1);
    if (start == 0) {
      Pn = sl[1 + kk] - lgS[0];
      float vv = (0 < xlb) ? lgadd(Pn, Pb) : LOGZERO;
      float nm = fmaxf(mrun, vv);
      srun = srun * __expf(mrun - nm) + __expf(vv - nm);
      mrun = nm;
    }
    int t0 = (start > 1) ? start : 1;
    for (int t = t0; t < Tt; ++t) {
      float xn = sl[t * 31 + 1 + kk] - lgS[t];
      float xb = blankLp[t];
      float pref = lastP1[t - 1];   // lastPsum == lastP1 bit-exactly
      float Pn2 = lgadd(Pn, pref) + xn;
      float Pb2 = lgadd(Pn, Pb) + xb;
      Pn = Pn2; Pb = Pb2;
      float vv = (t < xlb) ? lgadd(Pn, Pb) : LOGZERO;
      float nm = fmaxf(mrun, vv);
      srun = srun * __expf(mrun - nm) + __expf(vv - nm);
      mrun = nm;
    }
    curP = mrun + __logf(srun);
  }
  __syncthreads();   // LOGZERO fill + lastP1 complete

  if (tid < 64) {
    if (tid < CB) orow[beam[b * CB + tid]] = curP;
  }
  __syncthreads();
  if (tid == 0) {
    float eosv = (xlb >= 1) ? lastP1[xlb - 1] : 0.0f;
    orow[*eosp] = eosv;
    orow[*blankp] = LOGZERO;
  }
}

extern "C" void kernel_launch(void* const* d_in, const int* in_sizes, int n_in,
                              void* d_out, int out_size, void* d_ws, size_t ws_size,
                              hipStream_t stream) {
  (void)n_in; (void)out_size; (void)ws_size;
  const float* x    = (const float*)d_in[0];
  const float* W    = (const float*)d_in[1];
  const float* bias = (const float*)d_in[2];
  const int* xl     = (const int*)d_in[3];
  const int* beam   = (const int*)d_in[5];
  const int* blankp = (const int*)d_in[6];
  const int* eosp   = (const int*)d_in[7];
  const int Ly = in_sizes[4] / Bb;
  const int CB = in_sizes[5] / Bb;

  float* Ssum = (float*)d_ws;                                        // 64 KB
  float* selL = (float*)((char*)d_ws + (size_t)65536);               // BT*31*4 = 1.94 MB
  unsigned short* Xbf = (unsigned short*)((char*)d_ws + (size_t)2097152);   // 16 MB
  unsigned short* Wbf = (unsigned short*)((char*)d_ws + (size_t)18874368);  // 4 MB
  float* outf = (float*)d_out;

  hipMemsetAsync(Ssum, 0, BT * sizeof(float), stream);
  kConv<<<(BT * Dd + Vv * Dd) / 1024, 256, 0, stream>>>(x, W, Xbf, Wbf);
  kA<<<(BT / 128) * (Vv / 128), 256, 0, stream>>>(Xbf, Wbf, bias, beam, blankp, Ssum, selL, CB);
  kC<<<Bb, 256, 0, stream>>>(selL, Ssum, xl, beam, blankp, eosp, outf, Ly, CB);
}

// Round 3
// 386.487 us; speedup vs baseline: 1.4769x; 1.4769x over previous
//
#include <hip/hip_runtime.h>

#define LOGZERO -4290774016.0f   // -(65504^2), exactly representable in fp32

constexpr int Bb = 32, Tt = 512, Dd = 512, Vv = 4096;
constexpr int BT = Bb * Tt;

typedef __attribute__((ext_vector_type(8))) short short8;
typedef __attribute__((ext_vector_type(4))) float f32x4;

#define GLOBAL_AS __attribute__((address_space(1)))
#define LDS_AS    __attribute__((address_space(3)))

__device__ __forceinline__ unsigned short f2bf(float f) {
  unsigned int u = __float_as_uint(f);
  u += 0x7FFFu + ((u >> 16) & 1u);   // RNE
  return (unsigned short)(u >> 16);
}

__device__ __forceinline__ float lgadd(float a, float b) {
  float mx = fmaxf(a, b);
  float d  = fabsf(a - b);
  return mx + __logf(1.0f + __expf(-d));
}

// ---- x and W fp32 -> bf16 (one pass) ----
__global__ __launch_bounds__(256) void kConv(const float* __restrict__ x,
                                             const float* __restrict__ W,
                                             unsigned short* __restrict__ Xb,
                                             unsigned short* __restrict__ Wb) {
  size_t i = (size_t)(blockIdx.x * 256 + threadIdx.x) * 4;
  const float* src;
  unsigned short* dst;
  if (i < (size_t)BT * Dd) { src = x + i; dst = Xb + i; }
  else { size_t j = i - (size_t)BT * Dd; src = W + j; dst = Wb + j; }
  float4 v = *(const float4*)src;
  ushort4 h;
  h.x = f2bf(v.x); h.y = f2bf(v.y); h.z = f2bf(v.z); h.w = f2bf(v.w);
  *(ushort4*)dst = h;
}

// ---- m97-style 128x128 bf16 GEMM + fused exp-sum + beam-logit scatter ----
// grid: 4096 blocks; tileM = blk & 127 (A stripe pins to one XCD), tileN = blk >> 7.
__global__ __launch_bounds__(256) void kA(const unsigned short* __restrict__ Xb,
                                          const unsigned short* __restrict__ Wb,
                                          const float* __restrict__ bias,
                                          const int* __restrict__ beam,
                                          const int* __restrict__ blankp,
                                          float* __restrict__ Ssum,
                                          float* __restrict__ selL,
                                          int CB) {
  __shared__ unsigned short Ald[128 * 64];   // 16 KB, xor-swizzled 16B groups
  __shared__ unsigned short Bld[128 * 64];   // 16 KB
  __shared__ int   selv[31];
  __shared__ float selb[31];

  const int tid = threadIdx.x;
  const int tileM = blockIdx.x & 127;
  const int tileN = blockIdx.x >> 7;
  const int row0 = tileM * 128, col0 = tileN * 128;
  const int b = row0 >> 9;                   // 128 | 512: one batch per block

  if (tid < 31) {
    int v = (tid == 0) ? *blankp : beam[b * CB + tid - 1];
    selv[tid] = v;
    selb[tid] = bias[v];
  }

  const int lane = tid & 63, w = tid >> 6;
  const int ln15 = lane & 15, quad = lane >> 4;
  const int wr = w >> 1, wc = w & 1;

  // staging: wave w handles chunks w*8 .. w*8+7 (A: 0..15, B: 16..31)
  const int srow = lane >> 3;                // row within chunk
  const int g = lane & 7;                    // 16B group within row

  f32x4 acc[4][4];
  #pragma unroll
  for (int ct = 0; ct < 4; ++ct)
    #pragma unroll
    for (int rt = 0; rt < 4; ++rt) acc[ct][rt] = {0.f, 0.f, 0.f, 0.f};

  for (int k0 = 0; k0 < Dd; k0 += 64) {
    __syncthreads();   // prior-iter fragment reads done before overwrite
    #pragma unroll
    for (int j = 0; j < 8; ++j) {
      int c = w * 8 + j;
      bool isA = c < 16;
      int cc = isA ? c : c - 16;
      int r = cc * 8 + srow;                 // 0..127
      int kk = k0 + ((g ^ (r & 7)) << 3);    // swizzled global k-offset
      const unsigned short* gp = isA ? (Xb + (size_t)(row0 + r) * Dd + kk)
                                     : (Wb + (size_t)(col0 + r) * Dd + kk);
      unsigned short* lp = (isA ? Ald : Bld) + cc * 512;   // 1 KB chunk base
      __builtin_amdgcn_global_load_lds((const GLOBAL_AS void*)gp,
                                       (LDS_AS void*)lp, 16, 0, 0);
    }
    __syncthreads();   // drain DMA

    #pragma unroll
    for (int ks = 0; ks < 64; ks += 32) {
      short8 af[4], bf[4];
      #pragma unroll
      for (int rt = 0; rt < 4; ++rt) {
        int r = wr * 64 + rt * 16 + ln15;
        int grp = (ks >> 3) + quad;
        af[rt] = *(const short8*)&Ald[r * 64 + ((grp ^ (r & 7)) << 3)];
      }
      #pragma unroll
      for (int ct = 0; ct < 4; ++ct) {
        int cl = wc * 64 + ct * 16 + ln15;
        int grp = (ks >> 3) + quad;
        bf[ct] = *(const short8*)&Bld[cl * 64 + ((grp ^ (cl & 7)) << 3)];
      }
      #pragma unroll
      for (int ct = 0; ct < 4; ++ct)
        #pragma unroll
        for (int rt = 0; rt < 4; ++rt)
          acc[ct][rt] = __builtin_amdgcn_mfma_f32_16x16x32_bf16(af[rt], bf[ct], acc[ct][rt], 0, 0, 0);
    }
  }

  // ---- epilogue: row-wise sum(exp(logit+bias)) -> atomics; beam columns -> selL ----
  float bv[4];
  #pragma unroll
  for (int ct = 0; ct < 4; ++ct) bv[ct] = bias[col0 + wc * 64 + ct * 16 + ln15];

  #pragma unroll
  for (int rt = 0; rt < 4; ++rt) {
    #pragma unroll
    for (int r = 0; r < 4; ++r) {
      float s = 0.f;
      #pragma unroll
      for (int ct = 0; ct < 4; ++ct) s += __expf(acc[ct][rt][r] + bv[ct]);
      s += __shfl_xor(s, 1, 64);
      s += __shfl_xor(s, 2, 64);
      s += __shfl_xor(s, 4, 64);
      s += __shfl_xor(s, 8, 64);
      if (ln15 == 0)
        atomicAdd(&Ssum[row0 + wr * 64 + rt * 16 + quad * 4 + r], s);
    }
  }

  // beam scatter — ALL acc indices compile-time (no scratch demotion)
  const int tbase = (row0 & 511) + wr * 64;
  #pragma unroll
  for (int ct = 0; ct < 4; ++ct) {
    for (int s = 0; s < 31; ++s) {
      int local = selv[s] - col0 - wc * 64 - ct * 16;
      if (local >= 0 && local < 16 && ln15 == local) {
        float bvs = selb[s];
        #pragma unroll
        for (int rt = 0; rt < 4; ++rt)
          #pragma unroll
          for (int r = 0; r < 4; ++r) {
            int t = tbase + rt * 16 + quad * 4 + r;
            selL[((size_t)b * Tt + t) * 31 + s] = acc[ct][rt][r] + bvs;
          }
      }
    }
  }
}

// ---- CTC DP + output assembly. grid: B blocks x 256 threads ----
__global__ __launch_bounds__(256) void kC(const float* __restrict__ selL,
                                          const float* __restrict__ Ssum,
                                          const int* __restrict__ xl,
                                          const int* __restrict__ beam,
                                          const int* __restrict__ blankp,
                                          const int* __restrict__ eosp,
                                          float* __restrict__ out,
                                          int Ly, int CB) {
  __shared__ float sl[Tt * 31];     // 63.5 KB raw selected logits
  __shared__ float lgS[Tt];
  __shared__ float lastP1[Tt];
  __shared__ float blankLp[Tt];
  const int b = blockIdx.x, tid = threadIdx.x;

  for (int i = tid; i < Tt * 31; i += 256) sl[i] = selL[(size_t)b * Tt * 31 + i];
  for (int t = tid; t < Tt; t += 256) lgS[t] = __logf(Ssum[b * Tt + t]);
  __syncthreads();

  float* orow = out + (size_t)b * Vv;
  for (int i = tid; i < Vv; i += 256) orow[i] = LOGZERO;

  const int xlb = xl[b];
  float curP = LOGZERO;
  if (tid < 64) {
    const int lane = tid;
    float vloc[8];
    float run = 0.f;
    #pragma unroll
    for (int u = 0; u < 8; ++u) {
      int t = lane * 8 + u;
      float bl = sl[t * 31] - lgS[t];
      blankLp[t] = bl;
      run += bl;
      vloc[u] = run;
    }
    float inc = run;
    #pragma unroll
    for (int off = 1; off < 64; off <<= 1) {
      float o = __shfl_up(inc, off, 64);
      if (lane >= off) inc += o;
    }
    float excl = inc - run;
    #pragma unroll
    for (int u = 0; u < 8; ++u) lastP1[lane * 8 + u] = vloc[u] + excl;

    const int kk = (lane < CB) ? lane : (CB - 1);
    float Pn = LOGZERO, Pb = LOGZERO;
    float mrun = -3.0e38f, srun = 0.0f;
    int start = (Ly < Tt - 1) ? Ly : (Tt - 1);
    if (start == 0) {
      Pn = sl[1 + kk] - lgS[0];
      float vv = (0 < xlb) ? lgadd(Pn, Pb) : LOGZERO;
      float nm = fmaxf(mrun, vv);
      srun = srun * __expf(mrun - nm) + __expf(vv - nm);
      mrun = nm;
    }
    int t0 = (start > 1) ? start : 1;
    for (int t = t0; t < Tt; ++t) {
      float xn = sl[t * 31 + 1 + kk] - lgS[t];
      float xb = blankLp[t];
      float pref = lastP1[t - 1];   // lastPsum == lastP1 bit-exactly
      float Pn2 = lgadd(Pn, pref) + xn;
      float Pb2 = lgadd(Pn, Pb) + xb;
      Pn = Pn2; Pb = Pb2;
      float vv = (t < xlb) ? lgadd(Pn, Pb) : LOGZERO;
      float nm = fmaxf(mrun, vv);
      srun = srun * __expf(mrun - nm) + __expf(vv - nm);
      mrun = nm;
    }
    curP = mrun + __logf(srun);
  }
  __syncthreads();   // LOGZERO fill + lastP1 complete

  if (tid < 64) {
    if (tid < CB) orow[beam[b * CB + tid]] = curP;
  }
  __syncthreads();
  if (tid == 0) {
    float eosv = (xlb >= 1) ? lastP1[xlb - 1] : 0.0f;
    orow[*eosp] = eosv;
    orow[*blankp] = LOGZERO;
  }
}

extern "C" void kernel_launch(void* const* d_in, const int* in_sizes, int n_in,
                              void* d_out, int out_size, void* d_ws, size_t ws_size,
                              hipStream_t stream) {
  (void)n_in; (void)out_size; (void)ws_size;
  const float* x    = (const float*)d_in[0];
  const float* W    = (const float*)d_in[1];
  const float* bias = (const float*)d_in[2];
  const int* xl     = (const int*)d_in[3];
  const int* beam   = (const int*)d_in[5];
  const int* blankp = (const int*)d_in[6];
  const int* eosp   = (const int*)d_in[7];
  const int Ly = in_sizes[4] / Bb;
  const int CB = in_sizes[5] / Bb;

  float* Ssum = (float*)d_ws;                                        // 64 KB
  float* selL = (float*)((char*)d_ws + (size_t)65536);               // BT*31*4 = 1.94 MB
  unsigned short* Xbf = (unsigned short*)((char*)d_ws + (size_t)2097152);   // 16 MB
  unsigned short* Wbf = (unsigned short*)((char*)d_ws + (size_t)18874368);  // 4 MB
  float* outf = (float*)d_out;

  hipMemsetAsync(Ssum, 0, BT * sizeof(float), stream);
  kConv<<<(BT * Dd + Vv * Dd) / 1024, 256, 0, stream>>>(x, W, Xbf, Wbf);
  kA<<<(BT / 128) * (Vv / 128), 256, 0, stream>>>(Xbf, Wbf, bias, beam, blankp, Ssum, selL, CB);
  kC<<<Bb, 256, 0, stream>>>(selL, Ssum, xl, beam, blankp, eosp, outf, Ly, CB);
}